// Round 5
// baseline (312.991 us; speedup 1.0000x reference)
//
#include <hip/hip_runtime.h>
#include <hip/hip_bf16.h>
#include <math.h>

// GCN: coarse bucket sort (512 nodes/bucket) -> per-bucket exact CSR ->
// wave-per-node pull aggregation with dense layers fused into epilogues.
// Features pre-scaled by dinv[src]; all layer scalings folded.

#define CW    512     // nodes per coarse bucket
#define CSH   9
#define MAXBUKC 256   // supports n <= 131072 (17-bit src packing)

static inline int cdiv(int a, int b) { return (a + b - 1) / b; }

// ---------------- bucket build ----------------

__global__ void __launch_bounds__(256) k_bhist(const int* __restrict__ dst,
                                               int* __restrict__ bcnt, int e, int nbuk) {
    __shared__ int lh[MAXBUKC];
    for (int b = threadIdx.x; b < nbuk; b += 256) lh[b] = 0;
    __syncthreads();
    int base = blockIdx.x * 4096;
#pragma unroll
    for (int j = 0; j < 16; j++) {
        int i = base + j * 256 + threadIdx.x;
        if (i < e) atomicAdd(&lh[dst[i] >> CSH], 1);
    }
    __syncthreads();
    for (int b = threadIdx.x; b < nbuk; b += 256) {
        int c = lh[b];
        if (c) atomicAdd(&bcnt[b], c);
    }
}

__global__ void __launch_bounds__(256) k_bscan(const int* __restrict__ bcnt,
                                               int* __restrict__ boff, int* __restrict__ gcur,
                                               int nbuk, int e) {
    __shared__ int sh[256];
    int t = threadIdx.x;
    int v = (t < nbuk) ? bcnt[t] : 0;
    sh[t] = v;
    __syncthreads();
    for (int o = 1; o < 256; o <<= 1) {
        int u = (t >= o) ? sh[t - o] : 0;
        __syncthreads();
        sh[t] += u;
        __syncthreads();
    }
    if (t < nbuk) { int ex = sh[t] - v; boff[t] = ex; gcur[t] = ex; }
    if (t == 0) boff[nbuk] = e;
}

// pack (dstLocal<<17)|src ; dstLocal < 512
__global__ void __launch_bounds__(256) k_bscatter(const int* __restrict__ src,
                                                  const int* __restrict__ dst,
                                                  int* __restrict__ gcur,
                                                  int* __restrict__ ebuf, int e, int nbuk) {
    __shared__ int lh[MAXBUKC];
    __shared__ int lb[MAXBUKC];
    for (int b = threadIdx.x; b < nbuk; b += 256) lh[b] = 0;
    __syncthreads();
    int base = blockIdx.x * 8192;
#pragma unroll
    for (int j = 0; j < 32; j++) {
        int i = base + j * 256 + threadIdx.x;
        if (i < e) atomicAdd(&lh[dst[i] >> CSH], 1);
    }
    __syncthreads();
    for (int b = threadIdx.x; b < nbuk; b += 256) {
        int c = lh[b];
        lb[b] = c ? atomicAdd(&gcur[b], c) : 0;
        lh[b] = 0;
    }
    __syncthreads();
#pragma unroll
    for (int j = 0; j < 32; j++) {
        int i = base + j * 256 + threadIdx.x;
        if (i < e) {
            int d = dst[i], s = src[i];
            int b = d >> CSH;
            int r = atomicAdd(&lh[b], 1);
            ebuf[lb[b] + r] = ((d & (CW - 1)) << 17) | s;
        }
    }
}

// ---------------- per-bucket exact CSR + dinv (512 threads) ----------------

__global__ void __launch_bounds__(CW) k_csr2(const int* __restrict__ ebuf,
                                             const int* __restrict__ boff,
                                             int* __restrict__ rowstart,
                                             int* __restrict__ csr_src,
                                             float* __restrict__ dinv, int n, int e) {
    __shared__ int cnt[CW];
    __shared__ int offs[CW];
    int t = threadIdx.x;
    cnt[t] = 0;
    __syncthreads();
    int beg = boff[blockIdx.x], end = boff[blockIdx.x + 1];
    for (int k = beg + t; k < end; k += CW)
        atomicAdd(&cnt[ebuf[k] >> 17], 1);
    __syncthreads();
    int v = cnt[t];
    offs[t] = v;
    __syncthreads();
    for (int o = 1; o < CW; o <<= 1) {
        int u = (t >= o) ? offs[t - o] : 0;
        __syncthreads();
        offs[t] += u;
        __syncthreads();
    }
    int ex = offs[t] - v;   // exclusive prefix
    int node = blockIdx.x * CW + t;
    if (node < n) {
        rowstart[node] = beg + ex;
        dinv[node] = rsqrtf((float)v + 1.0f);
    }
    cnt[t] = ex;            // reuse as cursor
    __syncthreads();
    for (int k = beg + t; k < end; k += CW) {
        int pv = ebuf[k];
        int dl = pv >> 17, s = pv & 0x1FFFF;
        int r = atomicAdd(&cnt[dl], 1);
        csr_src[beg + r] = s;
    }
    if (blockIdx.x == 0 && t == 0) rowstart[n] = e;
}

// ---------------- pre-scale ----------------

__global__ void __launch_bounds__(256) k_xscale(const float* __restrict__ x,
                                                const float* __restrict__ dinv,
                                                float* __restrict__ xs, int n4) {
    int i = blockIdx.x * blockDim.x + threadIdx.x;
    if (i >= n4) return;
    float dd = dinv[i >> 2];
    float4 v = ((const float4*)x)[i];
    v.x *= dd; v.y *= dd; v.z *= dd; v.w *= dd;
    ((float4*)xs)[i] = v;
}

// ---------------- fused pull + dense ----------------

// Layer 1: wave per node. agg(xs,16) -> h1s[node][col] = relu(agg@W1+b1)[col] * dinv
__global__ void __launch_bounds__(256) k_pull16_d(const int* __restrict__ rowstart,
                                                  const int* __restrict__ csr_src,
                                                  const float* __restrict__ dinv,
                                                  const float* __restrict__ xs,
                                                  const float* __restrict__ W1,
                                                  const float* __restrict__ b1,
                                                  float* __restrict__ h1s, int n) {
    int wid = (blockIdx.x * blockDim.x + threadIdx.x) >> 6;
    if (wid >= n) return;
    int lane = threadIdx.x & 63;
    int f4 = lane & 3;
    int col = lane & 31;
    // W1 column `col`, rows pre-permuted in consumption order (chunk = f4^m)
    float w1c[16];
#pragma unroll
    for (int m = 0; m < 4; m++) {
        int c = f4 ^ m;
#pragma unroll
        for (int q = 0; q < 4; q++) w1c[m * 4 + q] = W1[(c * 4 + q) * 32 + col];
    }
    float bb = b1[col];

    int beg = rowstart[wid], end = rowstart[wid + 1];
    const float4* x4 = (const float4*)xs;
    float4 acc = make_float4(0.f, 0.f, 0.f, 0.f);
    for (int k = beg + (lane >> 2); k < end; k += 16) {
        int s = csr_src[k];
        float4 v = x4[(size_t)s * 4 + f4];
        acc.x += v.x; acc.y += v.y; acc.z += v.z; acc.w += v.w;
    }
#pragma unroll
    for (int off = 4; off < 64; off <<= 1) {
        acc.x += __shfl_xor(acc.x, off);
        acc.y += __shfl_xor(acc.y, off);
        acc.z += __shfl_xor(acc.z, off);
        acc.w += __shfl_xor(acc.w, off);
    }
    // self term + normalize: every lane holds full agg chunk f4
    float dd = dinv[wid];
    float4 sv = x4[(size_t)wid * 4 + f4];
    acc.x = (acc.x + sv.x) * dd;
    acc.y = (acc.y + sv.y) * dd;
    acc.z = (acc.z + sv.z) * dd;
    acc.w = (acc.w + sv.w) * dd;
    // dense 16->32: lane (col = lane&31) computes column col
    float o = bb;
#pragma unroll
    for (int m = 0; m < 4; m++) {
        float ax = __shfl_xor(acc.x, m);
        float ay = __shfl_xor(acc.y, m);
        float az = __shfl_xor(acc.z, m);
        float aw = __shfl_xor(acc.w, m);
        o += ax * w1c[m * 4 + 0] + ay * w1c[m * 4 + 1] + az * w1c[m * 4 + 2] + aw * w1c[m * 4 + 3];
    }
    if (lane < 32) h1s[(size_t)wid * 32 + col] = fmaxf(o, 0.f) * dd;
}

// Layer 2 (+W3): agg(h1s,32) -> t2[node] = (relu(agg@W2+b2) @ W3) * dinv
__global__ void __launch_bounds__(256) k_pull32_d(const int* __restrict__ rowstart,
                                                  const int* __restrict__ csr_src,
                                                  const float* __restrict__ dinv,
                                                  const float* __restrict__ h1s,
                                                  const float* __restrict__ W2,
                                                  const float* __restrict__ b2,
                                                  const float* __restrict__ W3,
                                                  float* __restrict__ t2, int n) {
    int wid = (blockIdx.x * blockDim.x + threadIdx.x) >> 6;
    if (wid >= n) return;
    int lane = threadIdx.x & 63;
    int f4 = lane & 7;
    // W2 column `lane`, rows pre-permuted (chunk = f4^m)
    float w2c[32];
#pragma unroll
    for (int m = 0; m < 8; m++) {
        int c = f4 ^ m;
#pragma unroll
        for (int q = 0; q < 4; q++) w2c[m * 4 + q] = W2[(c * 4 + q) * 64 + lane];
    }
    float bb = b2[lane];
    float w3l = W3[lane];

    int beg = rowstart[wid], end = rowstart[wid + 1];
    const float4* h4 = (const float4*)h1s;
    float4 acc = make_float4(0.f, 0.f, 0.f, 0.f);
    for (int k = beg + (lane >> 3); k < end; k += 8) {
        int s = csr_src[k];
        float4 v = h4[(size_t)s * 8 + f4];
        acc.x += v.x; acc.y += v.y; acc.z += v.z; acc.w += v.w;
    }
#pragma unroll
    for (int off = 8; off < 64; off <<= 1) {
        acc.x += __shfl_xor(acc.x, off);
        acc.y += __shfl_xor(acc.y, off);
        acc.z += __shfl_xor(acc.z, off);
        acc.w += __shfl_xor(acc.w, off);
    }
    float dd = dinv[wid];
    float4 sv = h4[(size_t)wid * 8 + f4];
    acc.x = (acc.x + sv.x) * dd;
    acc.y = (acc.y + sv.y) * dd;
    acc.z = (acc.z + sv.z) * dd;
    acc.w = (acc.w + sv.w) * dd;
    // dense 32->64 (col = lane) + relu + W3 dot
    float o = bb;
#pragma unroll
    for (int m = 0; m < 8; m++) {
        float ax = __shfl_xor(acc.x, m);
        float ay = __shfl_xor(acc.y, m);
        float az = __shfl_xor(acc.z, m);
        float aw = __shfl_xor(acc.w, m);
        o += ax * w2c[m * 4 + 0] + ay * w2c[m * 4 + 1] + az * w2c[m * 4 + 2] + aw * w2c[m * 4 + 3];
    }
    float p = fmaxf(o, 0.f) * w3l;
#pragma unroll
    for (int off = 1; off < 64; off <<= 1) p += __shfl_xor(p, off);
    if (lane == 0) t2[wid] = p * dd;
}

// Layer 3: scalar pull over t2 + bias + sigmoid
__global__ void __launch_bounds__(256) k_pull1_sig(const int* __restrict__ rowstart,
                                                   const int* __restrict__ csr_src,
                                                   const float* __restrict__ dinv,
                                                   const float* __restrict__ t2,
                                                   const float* __restrict__ b3,
                                                   float* __restrict__ out, int n) {
    int wid = (blockIdx.x * blockDim.x + threadIdx.x) >> 6;
    if (wid >= n) return;
    int lane = threadIdx.x & 63;
    int beg = rowstart[wid], end = rowstart[wid + 1];
    float acc = 0.f;
    for (int k = beg + lane; k < end; k += 64) acc += t2[csr_src[k]];
#pragma unroll
    for (int off = 1; off < 64; off <<= 1) acc += __shfl_xor(acc, off);
    if (lane == 0) {
        float v = (acc + t2[wid]) * dinv[wid] + b3[0];
        out[wid] = 1.0f / (1.0f + expf(-v));
    }
}

// ---------------- launch ----------------

extern "C" void kernel_launch(void* const* d_in, const int* in_sizes, int n_in,
                              void* d_out, int out_size, void* d_ws, size_t ws_size,
                              hipStream_t stream) {
    const float* x  = (const float*)d_in[0];
    const int*   ei = (const int*)d_in[1];
    const float* W1 = (const float*)d_in[2];
    const float* b1 = (const float*)d_in[3];
    const float* W2 = (const float*)d_in[4];
    const float* b2 = (const float*)d_in[5];
    const float* W3 = (const float*)d_in[6];
    const float* b3 = (const float*)d_in[7];

    const int n = in_sizes[0] / 16;
    const int e = in_sizes[1] / 2;
    const int* src = ei;
    const int* dst = ei + e;
    const int nbuk = cdiv(n, CW);   // 196 for n=100000

    auto rup = [](size_t v) { return (v + 15) & ~(size_t)15; };
    char* wp = (char*)d_ws;
    auto alloc = [&](size_t elems) { void* p = wp; wp += rup(elems) * 4; return p; };
    int*   bcnt     = (int*)  alloc(MAXBUKC);
    int*   boff     = (int*)  alloc(MAXBUKC + 1);
    int*   gcur     = (int*)  alloc(MAXBUKC);
    float* dinv     = (float*)alloc(n);
    int*   rowstart = (int*)  alloc(n + 1);
    int*   ebuf     = (int*)  alloc(e);
    int*   csr_src  = (int*)  alloc(e);
    float* xs       = (float*)alloc((size_t)16 * n);
    float* h1s      = (float*)alloc((size_t)32 * n);
    float* t2       = (float*)alloc(n);

    float* out = (float*)d_out;
    const int B = 256;
    const int pullGrid = cdiv(n * 64, B);

    hipMemsetAsync(bcnt, 0, MAXBUKC * 4, stream);
    k_bhist<<<cdiv(e, 4096), B, 0, stream>>>(dst, bcnt, e, nbuk);
    k_bscan<<<1, 256, 0, stream>>>(bcnt, boff, gcur, nbuk, e);
    k_bscatter<<<cdiv(e, 8192), B, 0, stream>>>(src, dst, gcur, ebuf, e, nbuk);
    k_csr2<<<nbuk, CW, 0, stream>>>(ebuf, boff, rowstart, csr_src, dinv, n, e);
    k_xscale<<<cdiv(n * 4, B), B, 0, stream>>>(x, dinv, xs, n * 4);

    k_pull16_d<<<pullGrid, B, 0, stream>>>(rowstart, csr_src, dinv, xs, W1, b1, h1s, n);
    k_pull32_d<<<pullGrid, B, 0, stream>>>(rowstart, csr_src, dinv, h1s, W2, b2, W3, t2, n);
    k_pull1_sig<<<pullGrid, B, 0, stream>>>(rowstart, csr_src, dinv, t2, b3, out, n);
}

// Round 6
// 258.973 us; speedup vs baseline: 1.2086x; 1.2086x over previous
//
#include <hip/hip_runtime.h>
#include <hip/hip_bf16.h>
#include <math.h>

// GCN: coarse bucket sort (512 nodes/bucket) -> per-bucket exact CSR ->
// wave-per-node pull aggregation (bf16-compressed features, fp32 accum)
// with dense layers fused into epilogues (coalesced weight loads,
// direct-index shfl broadcasts).

#define CW    512
#define CSH   9
#define MAXBUKC 256   // n <= 131072 (17-bit src packing)

static inline int cdiv(int a, int b) { return (a + b - 1) / b; }

// bf16 helpers (RNE)
__device__ inline unsigned int bf16_rn(float f) {
    unsigned int u = __float_as_uint(f);
    return (u + 0x7fffu + ((u >> 16) & 1u)) >> 16;
}
#define BLO(u) __uint_as_float((u) << 16)
#define BHI(u) __uint_as_float((u) & 0xffff0000u)

// ---------------- bucket build ----------------

__global__ void __launch_bounds__(256) k_bhist(const int* __restrict__ dst,
                                               int* __restrict__ bcnt, int e, int nbuk) {
    __shared__ int lh[MAXBUKC];
    for (int b = threadIdx.x; b < nbuk; b += 256) lh[b] = 0;
    __syncthreads();
    int base = blockIdx.x * 4096;
#pragma unroll
    for (int j = 0; j < 16; j++) {
        int i = base + j * 256 + threadIdx.x;
        if (i < e) atomicAdd(&lh[dst[i] >> CSH], 1);
    }
    __syncthreads();
    for (int b = threadIdx.x; b < nbuk; b += 256) {
        int c = lh[b];
        if (c) atomicAdd(&bcnt[b], c);
    }
}

__global__ void __launch_bounds__(256) k_bscan(const int* __restrict__ bcnt,
                                               int* __restrict__ boff, int* __restrict__ gcur,
                                               int nbuk, int e) {
    __shared__ int sh[256];
    int t = threadIdx.x;
    int v = (t < nbuk) ? bcnt[t] : 0;
    sh[t] = v;
    __syncthreads();
    for (int o = 1; o < 256; o <<= 1) {
        int u = (t >= o) ? sh[t - o] : 0;
        __syncthreads();
        sh[t] += u;
        __syncthreads();
    }
    if (t < nbuk) { int ex = sh[t] - v; boff[t] = ex; gcur[t] = ex; }
    if (t == 0) boff[nbuk] = e;
}

__global__ void __launch_bounds__(256) k_bscatter(const int* __restrict__ src,
                                                  const int* __restrict__ dst,
                                                  int* __restrict__ gcur,
                                                  int* __restrict__ ebuf, int e, int nbuk) {
    __shared__ int lh[MAXBUKC];
    __shared__ int lb[MAXBUKC];
    for (int b = threadIdx.x; b < nbuk; b += 256) lh[b] = 0;
    __syncthreads();
    int base = blockIdx.x * 8192;
#pragma unroll
    for (int j = 0; j < 32; j++) {
        int i = base + j * 256 + threadIdx.x;
        if (i < e) atomicAdd(&lh[dst[i] >> CSH], 1);
    }
    __syncthreads();
    for (int b = threadIdx.x; b < nbuk; b += 256) {
        int c = lh[b];
        lb[b] = c ? atomicAdd(&gcur[b], c) : 0;
        lh[b] = 0;
    }
    __syncthreads();
#pragma unroll
    for (int j = 0; j < 32; j++) {
        int i = base + j * 256 + threadIdx.x;
        if (i < e) {
            int d = dst[i], s = src[i];
            int b = d >> CSH;
            int r = atomicAdd(&lh[b], 1);
            ebuf[lb[b] + r] = ((d & (CW - 1)) << 17) | s;
        }
    }
}

// ---------------- per-bucket exact CSR + dinv ----------------

__global__ void __launch_bounds__(CW) k_csr2(const int* __restrict__ ebuf,
                                             const int* __restrict__ boff,
                                             int* __restrict__ rowstart,
                                             int* __restrict__ csr_src,
                                             float* __restrict__ dinv, int n, int e) {
    __shared__ int cnt[CW];
    __shared__ int offs[CW];
    int t = threadIdx.x;
    cnt[t] = 0;
    __syncthreads();
    int beg = boff[blockIdx.x], end = boff[blockIdx.x + 1];
    for (int k = beg + t; k < end; k += CW)
        atomicAdd(&cnt[ebuf[k] >> 17], 1);
    __syncthreads();
    int v = cnt[t];
    offs[t] = v;
    __syncthreads();
    for (int o = 1; o < CW; o <<= 1) {
        int u = (t >= o) ? offs[t - o] : 0;
        __syncthreads();
        offs[t] += u;
        __syncthreads();
    }
    int ex = offs[t] - v;
    int node = blockIdx.x * CW + t;
    if (node < n) {
        rowstart[node] = beg + ex;
        dinv[node] = rsqrtf((float)v + 1.0f);
    }
    cnt[t] = ex;
    __syncthreads();
    for (int k = beg + t; k < end; k += CW) {
        int pv = ebuf[k];
        int dl = pv >> 17, s = pv & 0x1FFFF;
        int r = atomicAdd(&cnt[dl], 1);
        csr_src[beg + r] = s;
    }
    if (blockIdx.x == 0 && t == 0) rowstart[n] = e;
}

// ---------------- pre-scale + bf16 pack: xs[i] = bf16(x[i]*dinv[i]) ----------------

__global__ void __launch_bounds__(256) k_xscale(const float* __restrict__ x,
                                                const float* __restrict__ dinv,
                                                unsigned int* __restrict__ xs, int n4) {
    int i = blockIdx.x * blockDim.x + threadIdx.x;
    if (i >= n4) return;
    float dd = dinv[i >> 2];
    float4 v = ((const float4*)x)[i];
    uint2 o;
    o.x = bf16_rn(v.x * dd) | (bf16_rn(v.y * dd) << 16);
    o.y = bf16_rn(v.z * dd) | (bf16_rn(v.w * dd) << 16);
    ((uint2*)xs)[i] = o;
}

// ---------------- Layer 1: agg(xs bf16,16) -> dense 16->32 relu -> h1s bf16 ----------------
// 2 lanes/edge (uint4 = 8 bf16 each), 32 edges in flight per wave.

__global__ void __launch_bounds__(256) k_pull16_d(const int* __restrict__ rowstart,
                                                  const int* __restrict__ csr_src,
                                                  const float* __restrict__ dinv,
                                                  const unsigned int* __restrict__ xs,
                                                  const float* __restrict__ W1,
                                                  const float* __restrict__ b1,
                                                  unsigned short* __restrict__ h1s, int n) {
    int wid = (blockIdx.x * blockDim.x + threadIdx.x) >> 6;
    if (wid >= n) return;
    int lane = threadIdx.x & 63;
    int half = lane & 1;
    int beg = rowstart[wid], end = rowstart[wid + 1];
    const uint4* x4 = (const uint4*)xs;   // 2 uint4 per node row
    float acc[8];
#pragma unroll
    for (int i = 0; i < 8; i++) acc[i] = 0.f;
    for (int k = beg + (lane >> 1); k < end; k += 32) {
        int s = csr_src[k];
        uint4 v = x4[(size_t)s * 2 + half];
        acc[0] += BLO(v.x); acc[1] += BHI(v.x);
        acc[2] += BLO(v.y); acc[3] += BHI(v.y);
        acc[4] += BLO(v.z); acc[5] += BHI(v.z);
        acc[6] += BLO(v.w); acc[7] += BHI(v.w);
    }
#pragma unroll
    for (int off = 2; off < 64; off <<= 1)
#pragma unroll
        for (int i = 0; i < 8; i++) acc[i] += __shfl_xor(acc[i], off);
    // self term + normalize; every lane holds chunk (lane&1): cols half*8..half*8+7
    float dd = dinv[wid];
    {
        uint4 sv = x4[(size_t)wid * 2 + half];
        acc[0] += BLO(sv.x); acc[1] += BHI(sv.x);
        acc[2] += BLO(sv.y); acc[3] += BHI(sv.y);
        acc[4] += BLO(sv.z); acc[5] += BHI(sv.z);
        acc[6] += BLO(sv.w); acc[7] += BHI(sv.w);
    }
#pragma unroll
    for (int i = 0; i < 8; i++) acc[i] *= dd;
    // dense 16->32: col = lane&31; coalesced natural-order weights
    int col = lane & 31;
    float o = b1[col];
#pragma unroll
    for (int k = 0; k < 16; k++) {
        float av = __shfl(acc[k & 7], (lane & 62) | (k >> 3));
        o += av * W1[k * 32 + col];
    }
    if (lane < 32)
        h1s[(size_t)wid * 32 + col] = (unsigned short)bf16_rn(fmaxf(o, 0.f) * dd);
}

// ---------------- Layer 2: agg(h1s bf16,32) -> dense 32->64 relu -> dot W3 -> t2 ----------------
// 4 lanes/edge (uint4 = 8 bf16 each), 16 edges in flight per wave.

__global__ void __launch_bounds__(256) k_pull32_d(const int* __restrict__ rowstart,
                                                  const int* __restrict__ csr_src,
                                                  const float* __restrict__ dinv,
                                                  const unsigned int* __restrict__ h1s,
                                                  const float* __restrict__ W2,
                                                  const float* __restrict__ b2,
                                                  const float* __restrict__ W3,
                                                  float* __restrict__ t2, int n) {
    int wid = (blockIdx.x * blockDim.x + threadIdx.x) >> 6;
    if (wid >= n) return;
    int lane = threadIdx.x & 63;
    int f4 = lane & 3;
    int beg = rowstart[wid], end = rowstart[wid + 1];
    const uint4* h4 = (const uint4*)h1s;  // 4 uint4 per node row
    float acc[8];
#pragma unroll
    for (int i = 0; i < 8; i++) acc[i] = 0.f;
    for (int k = beg + (lane >> 2); k < end; k += 16) {
        int s = csr_src[k];
        uint4 v = h4[(size_t)s * 4 + f4];
        acc[0] += BLO(v.x); acc[1] += BHI(v.x);
        acc[2] += BLO(v.y); acc[3] += BHI(v.y);
        acc[4] += BLO(v.z); acc[5] += BHI(v.z);
        acc[6] += BLO(v.w); acc[7] += BHI(v.w);
    }
#pragma unroll
    for (int off = 4; off < 64; off <<= 1)
#pragma unroll
        for (int i = 0; i < 8; i++) acc[i] += __shfl_xor(acc[i], off);
    float dd = dinv[wid];
    {
        uint4 sv = h4[(size_t)wid * 4 + f4];
        acc[0] += BLO(sv.x); acc[1] += BHI(sv.x);
        acc[2] += BLO(sv.y); acc[3] += BHI(sv.y);
        acc[4] += BLO(sv.z); acc[5] += BHI(sv.z);
        acc[6] += BLO(sv.w); acc[7] += BHI(sv.w);
    }
#pragma unroll
    for (int i = 0; i < 8; i++) acc[i] *= dd;
    // dense 32->64: col = lane; coalesced natural-order weights
    float o = b2[lane];
#pragma unroll
    for (int k = 0; k < 32; k++) {
        float av = __shfl(acc[k & 7], (lane & 60) | (k >> 3));
        o += av * W2[k * 64 + lane];
    }
    float p = fmaxf(o, 0.f) * W3[lane];
#pragma unroll
    for (int off = 1; off < 64; off <<= 1) p += __shfl_xor(p, off);
    if (lane == 0) t2[wid] = p * dd;
}

// ---------------- Layer 3: scalar pull + bias + sigmoid ----------------

__global__ void __launch_bounds__(256) k_pull1_sig(const int* __restrict__ rowstart,
                                                   const int* __restrict__ csr_src,
                                                   const float* __restrict__ dinv,
                                                   const float* __restrict__ t2,
                                                   const float* __restrict__ b3,
                                                   float* __restrict__ out, int n) {
    int wid = (blockIdx.x * blockDim.x + threadIdx.x) >> 6;
    if (wid >= n) return;
    int lane = threadIdx.x & 63;
    int beg = rowstart[wid], end = rowstart[wid + 1];
    float acc = 0.f;
    for (int k = beg + lane; k < end; k += 64) acc += t2[csr_src[k]];
#pragma unroll
    for (int off = 1; off < 64; off <<= 1) acc += __shfl_xor(acc, off);
    if (lane == 0) {
        float v = (acc + t2[wid]) * dinv[wid] + b3[0];
        out[wid] = 1.0f / (1.0f + expf(-v));
    }
}

// ---------------- launch ----------------

extern "C" void kernel_launch(void* const* d_in, const int* in_sizes, int n_in,
                              void* d_out, int out_size, void* d_ws, size_t ws_size,
                              hipStream_t stream) {
    const float* x  = (const float*)d_in[0];
    const int*   ei = (const int*)d_in[1];
    const float* W1 = (const float*)d_in[2];
    const float* b1 = (const float*)d_in[3];
    const float* W2 = (const float*)d_in[4];
    const float* b2 = (const float*)d_in[5];
    const float* W3 = (const float*)d_in[6];
    const float* b3 = (const float*)d_in[7];

    const int n = in_sizes[0] / 16;
    const int e = in_sizes[1] / 2;
    const int* src = ei;
    const int* dst = ei + e;
    const int nbuk = cdiv(n, CW);   // 196 for n=100000

    auto rup = [](size_t v) { return (v + 15) & ~(size_t)15; };
    char* wp = (char*)d_ws;
    auto alloc = [&](size_t elems) { void* p = wp; wp += rup(elems) * 4; return p; };
    int*   bcnt     = (int*)  alloc(MAXBUKC);
    int*   boff     = (int*)  alloc(MAXBUKC + 1);
    int*   gcur     = (int*)  alloc(MAXBUKC);
    float* dinv     = (float*)alloc(n);
    int*   rowstart = (int*)  alloc(n + 1);
    int*   ebuf     = (int*)  alloc(e);
    int*   csr_src  = (int*)  alloc(e);
    unsigned int* xs  = (unsigned int*)alloc((size_t)8 * n);    // 16 bf16 / node
    unsigned int* h1s = (unsigned int*)alloc((size_t)16 * n);   // 32 bf16 / node
    float* t2       = (float*)alloc(n);

    float* out = (float*)d_out;
    const int B = 256;
    const int pullGrid = cdiv(n * 64, B);

    hipMemsetAsync(bcnt, 0, MAXBUKC * 4, stream);
    k_bhist<<<cdiv(e, 4096), B, 0, stream>>>(dst, bcnt, e, nbuk);
    k_bscan<<<1, 256, 0, stream>>>(bcnt, boff, gcur, nbuk, e);
    k_bscatter<<<cdiv(e, 8192), B, 0, stream>>>(src, dst, gcur, ebuf, e, nbuk);
    k_csr2<<<nbuk, CW, 0, stream>>>(ebuf, boff, rowstart, csr_src, dinv, n, e);
    k_xscale<<<cdiv(n * 4, B), B, 0, stream>>>(x, dinv, xs, n * 4);

    k_pull16_d<<<pullGrid, B, 0, stream>>>(rowstart, csr_src, dinv, xs, W1, b1,
                                           (unsigned short*)h1s, n);
    k_pull32_d<<<pullGrid, B, 0, stream>>>(rowstart, csr_src, dinv, h1s, W2, b2, W3, t2, n);
    k_pull1_sig<<<pullGrid, B, 0, stream>>>(rowstart, csr_src, dinv, t2, b3, out, n);
}